// Round 7
// baseline (1470.829 us; speedup 1.0000x reference)
//
#include <hip/hip_runtime.h>
#include <hip/hip_bf16.h>

#define B_TOT 1024
#define L_T   128
#define DIN   5
#define HD    64
#define RESN  256
#define BDN   8
#define NMAT  9
#define NROWS (NMAT * RESN)                 // 2304
#define PLANE ((size_t)NROWS * RESN)        // 589824 elems per weight plane
#define NGRP  16
#define BG    64                            // batch per group
#define FPB   16                            // features per block
#define NTHR  256                           // 4 waves = 4 independent mt-planes
#define RB_GRP (2 * BG * RESN)              // uints per group (2 bufs, hi|lo packed)
#define WS_RB_OFF  (2 * PLANE * 2)          // bytes: after weight planes
#define WS_FLAG_OFF (WS_RB_OFF + (size_t)NGRP * RB_GRP * 4)

typedef __attribute__((ext_vector_type(8))) short bf16x8;
typedef __attribute__((ext_vector_type(4))) float f32x4;

__device__ __forceinline__ float fast_tanh(float x) {
    float e = __expf(2.0f * x);
    return 1.0f - 2.0f * __builtin_amdgcn_rcpf(e + 1.0f);
}

__device__ __forceinline__ unsigned pack_hilo(float v) {
    __hip_bfloat16 hi = __float2bfloat16(v);
    __hip_bfloat16 lo = __float2bfloat16(v - __bfloat162float(hi));
    return (unsigned)__builtin_bit_cast(unsigned short, hi) |
           ((unsigned)__builtin_bit_cast(unsigned short, lo) << 16);
}

// MALL-coherent accesses (same coherence point as agent-relaxed atomics).
__device__ __forceinline__ uint4 mall_load4(const unsigned* p) {
    uint4 r;
    asm volatile("global_load_dwordx4 %0, %1, off sc0 sc1" : "=v"(r) : "v"(p));
    return r;
}
__device__ __forceinline__ unsigned mall_load1(const unsigned* p) {
    unsigned r;
    asm volatile("global_load_dword %0, %1, off sc0 sc1" : "=v"(r) : "v"(p));
    return r;
}
__device__ __forceinline__ void mall_store1(unsigned* p, unsigned v) {
    asm volatile("global_store_dword %0, %1, off sc0 sc1" :: "v"(p), "v"(v) : "memory");
}
__device__ __forceinline__ void wait_vm0() {
    asm volatile("s_waitcnt vmcnt(0)" ::: "memory");
}

__global__ void conv_w(const float* __restrict__ B1, const float* __restrict__ B2,
                       __hip_bfloat16* __restrict__ wh, __hip_bfloat16* __restrict__ wl) {
    int idx = blockIdx.x * 256 + threadIdx.x;
    float v = (idx < RESN * RESN) ? B1[idx] : B2[idx - RESN * RESN];
    __hip_bfloat16 h = __float2bfloat16(v);
    wh[idx] = h;
    wl[idx] = __float2bfloat16(v - __bfloat162float(h));
}

// Weight-stationary persistent kernel. 256 blocks (1/CU), 16 groups x 16 blocks.
// 4 waves = 4 independent mt-planes (16 batch rows each); NO barriers in the
// main loop. Sync granularity = per-(block,wave) flag; consumers gate per
// kk-chunk (kk <-> producer blocks 2kk,2kk+1) and compute chunks as they land.
__global__ __launch_bounds__(NTHR, 1) void sde_ws(
    const float* __restrict__ Vn,  const float* __restrict__ inc,
    const float* __restrict__ W1,  const float* __restrict__ b1,
    const float* __restrict__ W2,  const float* __restrict__ b2,
    const float* __restrict__ rho1p, const float* __restrict__ rho2p,
    const float* __restrict__ rho3p, const float* __restrict__ rho4p,
    const float* __restrict__ rho5p,
    const float* __restrict__ lam1, const float* __restrict__ lam2,
    const float* __restrict__ Wr,  const float* __restrict__ brp,
    const __hip_bfloat16* __restrict__ wbf,   // hi plane; lo at +PLANE
    unsigned int* __restrict__ rbu,
    unsigned int* __restrict__ flags,         // [g][fb][mt] monotone counters
    float* __restrict__ out)
{
    __shared__ __align__(16) short wlds[2][NMAT][8][64][8];   // 147,456 B
    __shared__ __align__(16) short wrlds[2][8][4][8];         // 1,024 B (Wr frags)
    __shared__ __align__(16) short zfrag[8];                  // zero page

    const int tid  = threadIdx.x;
    const int mt   = tid >> 6;       // wave = mt-plane (batch 16mt..16mt+15)
    const int lane = tid & 63;
    const int n16  = lane & 15;
    const int quad = lane >> 4;
    const int bx   = blockIdx.x;
    const int g    = ((bx & 7) << 1) | (bx >> 7);   // perf-only XCD grouping
    const int fb   = (bx >> 3) & 15;
    const int f0   = fb * FPB;
    const int b0g  = g * BG;
    unsigned int* rbg   = rbu + (size_t)g * RB_GRP;
    unsigned int* flagp = flags + g * 64;           // 16 fb x 4 mt
    unsigned int* myflag = flagp + fb * 4 + mt;

    const float rho1 = rho1p[0], rho2 = rho2p[0], rho3 = rho3p[0],
                rho4 = rho4p[0], rho5 = rho5p[0];
    const float brv = brp[0];

    // ---- phase A: h = tanh(Vn@W1^T+b1) into LDS overlay ----
    float* hf  = (float*)&wlds[0][0][0][0][0];   // [64][66]
    float* vsh = hf + 64 * 66;                   // [64][16]
    for (int p = tid; p < BG * HD; p += NTHR) {
        int b = p >> 6, hh = p & 63;
        float s = b1[hh];
        #pragma unroll
        for (int d = 0; d < DIN; ++d) s += Vn[(b0g + b) * DIN + d] * W1[hh * DIN + d];
        hf[b * 66 + hh] = fast_tanh(s);
    }
    __syncthreads();
    // ---- phase B: V slice, wave-aligned (wave mt owns rows 16mt..16mt+15) ----
    {
        int b = 16 * mt + (lane >> 2);
        #pragma unroll
        for (int i = 0; i < 4; ++i) {
            int f = (lane & 3) * 4 + i;
            float s = b2[f0 + f];
            #pragma unroll 8
            for (int hh = 0; hh < HD; ++hh) s += hf[b * 66 + hh] * W2[(f0 + f) * HD + hh];
            vsh[b * 16 + f] = s;
            mall_store1(&rbg[(0 * BG + b) * RESN + f0 + f], pack_hilo(s));
        }
    }
    wait_vm0();   // this wave's r0 stores acked
    if (lane == 0)
        __hip_atomic_fetch_add(myflag, 1u, __ATOMIC_RELAXED, __HIP_MEMORY_SCOPE_AGENT);
    __syncthreads();

    // ---- phase C: per-lane state ----
    float rmast[4];   // fp32 master r: batch = 16mt+4quad+rg, feature = f0+n16
    #pragma unroll
    for (int rg = 0; rg < 4; ++rg) rmast[rg] = vsh[(16 * mt + 4 * quad + rg) * 16 + n16];
    const float l1c = lam1[f0 + n16];
    float l2c[BDN];
    #pragma unroll
    for (int k = 0; k < BDN; ++k) l2c[k] = lam2[k * RESN + f0 + n16];
    __syncthreads();

    // ---- phase D: weight slice -> fragment-major LDS; stage Wr frags ----
    for (int e = tid; e < 2 * NMAT * 8 * 64; e += NTHR) {
        int l  = e & 63;
        int kk = (e >> 6) & 7;
        int m  = e >> 9;
        int pl = (m >= NMAT) ? 1 : 0;
        int nt = m - pl * NMAT;
        const uint4* src = (const uint4*)(wbf + (size_t)pl * PLANE +
            (size_t)(nt * RESN + f0 + (l & 15)) * RESN + kk * 32 + (l >> 4) * 8);
        *(uint4*)&wlds[pl][nt][kk][l][0] = *src;
    }
    for (int p = tid; p < 512; p += NTHR) {   // Wr hi/lo 1-row B-frags
        int s = p >> 3, j = p & 7;
        int pl = s >> 5, kk = (s >> 2) & 7, q = s & 3;
        float v = Wr[kk * 32 + q * 8 + j];
        __hip_bfloat16 hi = __float2bfloat16(v);
        wrlds[pl][kk][q][j] = pl ? __builtin_bit_cast(short, __float2bfloat16(v - __bfloat162float(hi)))
                                 : __builtin_bit_cast(short, hi);
    }
    if (tid < 8) zfrag[tid] = 0;
    __syncthreads();

    const short* ph = (n16 == 0) ? &wrlds[0][0][quad][0] : &zfrag[0];
    const short* pw = (n16 == 0) ? &wrlds[1][0][quad][0] : &zfrag[0];
    const int    stp = (n16 == 0) ? 4 * 8 : 0;
    const unsigned* fladdr = (const unsigned*)(flagp + ((lane & 15) * 4 + mt));

    // ---- main loop: barrier-free, per-wave pipeline ----
    for (int t = 0; t < L_T - 1; ++t) {
        // dw loads (independent of exchange) issued first
        float dwv[4][8];
        #pragma unroll
        for (int rg = 0; rg < 4; ++rg) {
            const size_t bglob = (size_t)(b0g + 16 * mt + 4 * quad + rg) * (L_T * BDN);
            const float4 d0 = *(const float4*)(inc + bglob + (size_t)(t + 1) * BDN);
            const float4 d1 = *(const float4*)(inc + bglob + (size_t)(t + 1) * BDN + 4);
            dwv[rg][0] = d0.x; dwv[rg][1] = d0.y; dwv[rg][2] = d0.z; dwv[rg][3] = d0.w;
            dwv[rg][4] = d1.x; dwv[rg][5] = d1.y; dwv[rg][6] = d1.z; dwv[rg][7] = d1.w;
            if (t == 0) {
                const float4 e0 = *(const float4*)(inc + bglob);
                const float4 e1 = *(const float4*)(inc + bglob + 4);
                dwv[rg][0] += e0.x; dwv[rg][1] += e0.y; dwv[rg][2] += e0.z; dwv[rg][3] += e0.w;
                dwv[rg][4] += e1.x; dwv[rg][5] += e1.y; dwv[rg][6] += e1.z; dwv[rg][7] += e1.w;
            }
        }
        const unsigned want = (unsigned)(t + 1);
        const int cur = t & 1, nxt = cur ^ 1;
        const unsigned* rbc = rbg + (size_t)(cur * BG + 16 * mt + n16) * RESN + quad * 8;

        f32x4 acc[NMAT] = {};
        f32x4 accw = {};
        unsigned done = 0, guard = 0;
        while (done != 0xffu) {
            // poll all 16 producer flags of this mt-plane (one dword/lane)
            unsigned fv = mall_load1(fladdr);
            wait_vm0();
            unsigned long long bm = __ballot(fv >= want);
            unsigned m16 = (unsigned)bm & (unsigned)(bm >> 16) &
                           (unsigned)(bm >> 32) & (unsigned)(bm >> 48) & 0xffffu;
            unsigned pr = m16 & (m16 >> 1);
            unsigned kkm = 0;
            #pragma unroll
            for (int kk = 0; kk < 8; ++kk) kkm |= ((pr >> (2 * kk)) & 1u) << kk;
            kkm &= ~done;
            if (kkm == 0) {
                __builtin_amdgcn_s_sleep(1);
                if (++guard > (1u << 20)) break;   // bounded: no hang
                continue;
            }
            uint4 ua[16];
            #pragma unroll
            for (int kk = 0; kk < 8; ++kk)
                if (kkm & (1u << kk)) {
                    ua[2 * kk]     = mall_load4(rbc + kk * 32);
                    ua[2 * kk + 1] = mall_load4(rbc + kk * 32 + 4);
                }
            wait_vm0();
            #pragma unroll
            for (int kk = 0; kk < 8; ++kk)
                if (kkm & (1u << kk)) {
                    const uint4 a = ua[2 * kk], b = ua[2 * kk + 1];
                    unsigned hw[4], lw[4];
                    hw[0] = __builtin_amdgcn_perm(a.y, a.x, 0x05040100u);
                    hw[1] = __builtin_amdgcn_perm(a.w, a.z, 0x05040100u);
                    hw[2] = __builtin_amdgcn_perm(b.y, b.x, 0x05040100u);
                    hw[3] = __builtin_amdgcn_perm(b.w, b.z, 0x05040100u);
                    lw[0] = __builtin_amdgcn_perm(a.y, a.x, 0x07060302u);
                    lw[1] = __builtin_amdgcn_perm(a.w, a.z, 0x07060302u);
                    lw[2] = __builtin_amdgcn_perm(b.y, b.x, 0x07060302u);
                    lw[3] = __builtin_amdgcn_perm(b.w, b.z, 0x07060302u);
                    bf16x8 afh = __builtin_bit_cast(bf16x8, *(__attribute__((ext_vector_type(4))) unsigned*)hw);
                    bf16x8 afl = __builtin_bit_cast(bf16x8, *(__attribute__((ext_vector_type(4))) unsigned*)lw);
                    #pragma unroll
                    for (int nt = 0; nt < NMAT; ++nt) {
                        bf16x8 bh = *(const bf16x8*)&wlds[0][nt][kk][lane][0];
                        bf16x8 bl = *(const bf16x8*)&wlds[1][nt][kk][lane][0];
                        acc[nt] = __builtin_amdgcn_mfma_f32_16x16x32_bf16(afh, bh, acc[nt], 0, 0, 0);
                        acc[nt] = __builtin_amdgcn_mfma_f32_16x16x32_bf16(afl, bh, acc[nt], 0, 0, 0);
                        acc[nt] = __builtin_amdgcn_mfma_f32_16x16x32_bf16(afh, bl, acc[nt], 0, 0, 0);
                    }
                    if (fb == 0) {   // leader: out-projection folded in
                        bf16x8 wh8 = *(const bf16x8*)(ph + kk * stp);
                        bf16x8 wl8 = *(const bf16x8*)(pw + kk * stp);
                        accw = __builtin_amdgcn_mfma_f32_16x16x32_bf16(afh, wh8, accw, 0, 0, 0);
                        accw = __builtin_amdgcn_mfma_f32_16x16x32_bf16(afl, wh8, accw, 0, 0, 0);
                        accw = __builtin_amdgcn_mfma_f32_16x16x32_bf16(afh, wl8, accw, 0, 0, 0);
                    }
                }
            done |= kkm;
        }

        if (fb == 0 && n16 == 0) {
            #pragma unroll
            for (int rg = 0; rg < 4; ++rg)
                out[(size_t)(b0g + 16 * mt + 4 * quad + rg) * L_T + t] = accw[rg] + brv;
        }

        // combine, publish slice; per-wave ack + flag post (no barrier)
        #pragma unroll
        for (int rg = 0; rg < 4; ++rg) {
            const int bl_ = 16 * mt + 4 * quad + rg;
            float drift = fast_tanh(rho1 * acc[0][rg] + rho2 * l1c);
            float s = 0.0f;
            #pragma unroll
            for (int k = 0; k < BDN; ++k)
                s += fast_tanh(rho3 * acc[1 + k][rg] + rho4 * l2c[k]) * dwv[rg][k];
            float rn = rmast[rg] + drift + rho5 * s;
            rmast[rg] = rn;
            mall_store1(&rbg[(nxt * BG + bl_) * RESN + f0 + n16], pack_hilo(rn));
        }
        wait_vm0();
        if (lane == 0)
            __hip_atomic_fetch_add(myflag, 1u, __ATOMIC_RELAXED, __HIP_MEMORY_SCOPE_AGENT);
    }

    // ---- final column t = 127 (leader only; r_127 in buf 1) ----
    if (fb == 0) {
        const unsigned want = (unsigned)L_T;
        const unsigned* rbc = rbg + (size_t)(1 * BG + 16 * mt + n16) * RESN + quad * 8;
        f32x4 accw = {};
        unsigned done = 0, guard = 0;
        while (done != 0xffu) {
            unsigned fv = mall_load1(fladdr);
            wait_vm0();
            unsigned long long bm = __ballot(fv >= want);
            unsigned m16 = (unsigned)bm & (unsigned)(bm >> 16) &
                           (unsigned)(bm >> 32) & (unsigned)(bm >> 48) & 0xffffu;
            unsigned pr = m16 & (m16 >> 1);
            unsigned kkm = 0;
            #pragma unroll
            for (int kk = 0; kk < 8; ++kk) kkm |= ((pr >> (2 * kk)) & 1u) << kk;
            kkm &= ~done;
            if (kkm == 0) {
                __builtin_amdgcn_s_sleep(1);
                if (++guard > (1u << 20)) break;
                continue;
            }
            uint4 ua[16];
            #pragma unroll
            for (int kk = 0; kk < 8; ++kk)
                if (kkm & (1u << kk)) {
                    ua[2 * kk]     = mall_load4(rbc + kk * 32);
                    ua[2 * kk + 1] = mall_load4(rbc + kk * 32 + 4);
                }
            wait_vm0();
            #pragma unroll
            for (int kk = 0; kk < 8; ++kk)
                if (kkm & (1u << kk)) {
                    const uint4 a = ua[2 * kk], b = ua[2 * kk + 1];
                    unsigned hw[4], lw[4];
                    hw[0] = __builtin_amdgcn_perm(a.y, a.x, 0x05040100u);
                    hw[1] = __builtin_amdgcn_perm(a.w, a.z, 0x05040100u);
                    hw[2] = __builtin_amdgcn_perm(b.y, b.x, 0x05040100u);
                    hw[3] = __builtin_amdgcn_perm(b.w, b.z, 0x05040100u);
                    lw[0] = __builtin_amdgcn_perm(a.y, a.x, 0x07060302u);
                    lw[1] = __builtin_amdgcn_perm(a.w, a.z, 0x07060302u);
                    lw[2] = __builtin_amdgcn_perm(b.y, b.x, 0x07060302u);
                    lw[3] = __builtin_amdgcn_perm(b.w, b.z, 0x07060302u);
                    bf16x8 afh = __builtin_bit_cast(bf16x8, *(__attribute__((ext_vector_type(4))) unsigned*)hw);
                    bf16x8 afl = __builtin_bit_cast(bf16x8, *(__attribute__((ext_vector_type(4))) unsigned*)lw);
                    bf16x8 wh8 = *(const bf16x8*)(ph + kk * stp);
                    bf16x8 wl8 = *(const bf16x8*)(pw + kk * stp);
                    accw = __builtin_amdgcn_mfma_f32_16x16x32_bf16(afh, wh8, accw, 0, 0, 0);
                    accw = __builtin_amdgcn_mfma_f32_16x16x32_bf16(afl, wh8, accw, 0, 0, 0);
                    accw = __builtin_amdgcn_mfma_f32_16x16x32_bf16(afh, wl8, accw, 0, 0, 0);
                }
            done |= kkm;
        }
        if (n16 == 0) {
            #pragma unroll
            for (int rg = 0; rg < 4; ++rg)
                out[(size_t)(b0g + 16 * mt + 4 * quad + rg) * L_T + (L_T - 1)] = accw[rg] + brv;
        }
    }
}

extern "C" void kernel_launch(void* const* d_in, const int* in_sizes, int n_in,
                              void* d_out, int out_size, void* d_ws, size_t ws_size,
                              hipStream_t stream) {
    const float* Vn   = (const float*)d_in[0];
    const float* inc  = (const float*)d_in[1];
    const float* W1   = (const float*)d_in[2];
    const float* b1   = (const float*)d_in[3];
    const float* W2   = (const float*)d_in[4];
    const float* b2   = (const float*)d_in[5];
    const float* r1   = (const float*)d_in[6];
    const float* r2   = (const float*)d_in[7];
    const float* r3   = (const float*)d_in[8];
    const float* r4   = (const float*)d_in[9];
    const float* r5   = (const float*)d_in[10];
    const float* B1   = (const float*)d_in[11];
    const float* B2   = (const float*)d_in[12];
    const float* lam1 = (const float*)d_in[13];
    const float* lam2 = (const float*)d_in[14];
    const float* Wr   = (const float*)d_in[15];
    const float* br   = (const float*)d_in[16];

    __hip_bfloat16* wh    = (__hip_bfloat16*)d_ws;
    unsigned int*   rbu   = (unsigned int*)((char*)d_ws + WS_RB_OFF);
    unsigned int*   flags = (unsigned int*)((char*)d_ws + WS_FLAG_OFF);
    float* out = (float*)d_out;

    hipMemsetAsync(flags, 0, NGRP * 64 * sizeof(unsigned int), stream);
    conv_w<<<dim3(NROWS * RESN / 256), dim3(256), 0, stream>>>(B1, B2, wh, wh + PLANE);
    sde_ws<<<dim3(256), dim3(NTHR), 0, stream>>>(
        Vn, inc, W1, b1, W2, b2, r1, r2, r3, r4, r5, lam1, lam2, Wr, br,
        wh, rbu, flags, out);
}

// Round 8
// 873.088 us; speedup vs baseline: 1.6846x; 1.6846x over previous
//
#include <hip/hip_runtime.h>
#include <hip/hip_bf16.h>

#define B_TOT 1024
#define L_T   128
#define DIN   5
#define HD    64
#define RESN  256
#define BDN   8
#define NMAT  9
#define NROWS (NMAT * RESN)                 // 2304
#define PLANE ((size_t)NROWS * RESN)        // 589824 elems per weight plane
#define NGRP  16
#define BG    64                            // batch per group
#define FPB   16                            // features per block
#define NTHR  256                           // 4 waves = 4 independent mt-planes
#define RB_GRP (2 * BG * RESN)              // uints per group (2 bufs, hi|lo packed)
#define WS_RB_OFF  (2 * PLANE * 2)          // bytes: after weight planes
#define WS_FLAG_OFF (WS_RB_OFF + (size_t)NGRP * RB_GRP * 4)
#define FLAGS_PER_GRP 1024                  // 64 flags x 16-dword pad

typedef __attribute__((ext_vector_type(8))) short bf16x8;
typedef __attribute__((ext_vector_type(4))) float f32x4;

__device__ __forceinline__ float fast_tanh(float x) {
    float e = __expf(2.0f * x);
    return 1.0f - 2.0f * __builtin_amdgcn_rcpf(e + 1.0f);
}

__device__ __forceinline__ unsigned pack_hilo(float v) {
    __hip_bfloat16 hi = __float2bfloat16(v);
    __hip_bfloat16 lo = __float2bfloat16(v - __bfloat162float(hi));
    return (unsigned)__builtin_bit_cast(unsigned short, hi) |
           ((unsigned)__builtin_bit_cast(unsigned short, lo) << 16);
}

// MALL-coherent accesses (same coherence point as agent-relaxed atomics).
__device__ __forceinline__ uint4 mall_load4(const unsigned* p) {
    uint4 r;
    asm volatile("global_load_dwordx4 %0, %1, off sc0 sc1" : "=v"(r) : "v"(p));
    return r;
}
__device__ __forceinline__ unsigned mall_load1(const unsigned* p) {
    unsigned r;
    asm volatile("global_load_dword %0, %1, off sc0 sc1" : "=v"(r) : "v"(p));
    return r;
}
__device__ __forceinline__ void mall_store1(unsigned* p, unsigned v) {
    asm volatile("global_store_dword %0, %1, off sc0 sc1" :: "v"(p), "v"(v) : "memory");
}
__device__ __forceinline__ void wait_vm0() {
    asm volatile("s_waitcnt vmcnt(0)" ::: "memory");
}

// spin until ALL 16 producer flags of this mt-plane reach `want` (one dword/lane,
// 16 fb mapped on lane&15; single ballot; no partial gating)
__device__ __forceinline__ void spin_all(const unsigned* fladdr, unsigned want) {
    unsigned guard = 0;
    for (;;) {
        unsigned fv = mall_load1(fladdr);
        wait_vm0();
        if (__ballot(fv < want) == 0ull) break;
        __builtin_amdgcn_s_sleep(1);
        if (++guard > (1u << 20)) break;   // bounded: no hang if non-resident
    }
}

__global__ void conv_w(const float* __restrict__ B1, const float* __restrict__ B2,
                       __hip_bfloat16* __restrict__ wh, __hip_bfloat16* __restrict__ wl) {
    int idx = blockIdx.x * 256 + threadIdx.x;
    float v = (idx < RESN * RESN) ? B1[idx] : B2[idx - RESN * RESN];
    __hip_bfloat16 h = __float2bfloat16(v);
    wh[idx] = h;
    wl[idx] = __float2bfloat16(v - __bfloat162float(h));
}

// Weight-stationary persistent kernel. 256 blocks (1/CU), 16 groups x 16 blocks.
// 4 waves = 4 independent mt-planes. NO barriers in the main loop: per-(fb,mt)
// monotone flags (64B-padded), batched A-frag loads w/ single waitcnt (R6),
// rotating leader block computes the out column (amortizes straggler skew).
__global__ __launch_bounds__(NTHR, 1) void sde_ws(
    const float* __restrict__ Vn,  const float* __restrict__ inc,
    const float* __restrict__ W1,  const float* __restrict__ b1,
    const float* __restrict__ W2,  const float* __restrict__ b2,
    const float* __restrict__ rho1p, const float* __restrict__ rho2p,
    const float* __restrict__ rho3p, const float* __restrict__ rho4p,
    const float* __restrict__ rho5p,
    const float* __restrict__ lam1, const float* __restrict__ lam2,
    const float* __restrict__ Wr,  const float* __restrict__ brp,
    const __hip_bfloat16* __restrict__ wbf,   // hi plane; lo at +PLANE
    unsigned int* __restrict__ rbu,
    unsigned int* __restrict__ flags,         // [g][(fb*4+mt)*16] monotone
    float* __restrict__ out)
{
    __shared__ __align__(16) short wlds[2][NMAT][8][64][8];   // 147,456 B
    __shared__ __align__(16) short wrlds[2][8][4][8];         // 1,024 B (Wr frags)
    __shared__ __align__(16) short zfrag[8];                  // zero page

    const int tid  = threadIdx.x;
    const int mt   = tid >> 6;       // wave = mt-plane (batch 16mt..16mt+15)
    const int lane = tid & 63;
    const int n16  = lane & 15;
    const int quad = lane >> 4;
    const int bx   = blockIdx.x;
    const int g    = ((bx & 7) << 1) | (bx >> 7);   // perf-only XCD grouping
    const int fb   = (bx >> 3) & 15;
    const int f0   = fb * FPB;
    const int b0g  = g * BG;
    unsigned int* rbg    = rbu + (size_t)g * RB_GRP;
    unsigned int* flagp  = flags + g * FLAGS_PER_GRP;
    unsigned int* myflag = flagp + (fb * 4 + mt) * 16;
    const unsigned* fladdr = (const unsigned*)(flagp + ((lane & 15) * 4 + mt) * 16);

    const float rho1 = rho1p[0], rho2 = rho2p[0], rho3 = rho3p[0],
                rho4 = rho4p[0], rho5 = rho5p[0];
    const float brv = brp[0];

    // ---- phase A: h = tanh(Vn@W1^T+b1) into LDS overlay ----
    float* hf  = (float*)&wlds[0][0][0][0][0];   // [64][66]
    float* vsh = hf + 64 * 66;                   // [64][16]
    for (int p = tid; p < BG * HD; p += NTHR) {
        int b = p >> 6, hh = p & 63;
        float s = b1[hh];
        #pragma unroll
        for (int d = 0; d < DIN; ++d) s += Vn[(b0g + b) * DIN + d] * W1[hh * DIN + d];
        hf[b * 66 + hh] = fast_tanh(s);
    }
    __syncthreads();
    // ---- phase B: V slice, wave-aligned; publish r0; per-wave flag post ----
    {
        int b = 16 * mt + (lane >> 2);
        #pragma unroll
        for (int i = 0; i < 4; ++i) {
            int f = (lane & 3) * 4 + i;
            float s = b2[f0 + f];
            #pragma unroll 8
            for (int hh = 0; hh < HD; ++hh) s += hf[b * 66 + hh] * W2[(f0 + f) * HD + hh];
            vsh[b * 16 + f] = s;
            mall_store1(&rbg[(0 * BG + b) * RESN + f0 + f], pack_hilo(s));
        }
    }
    wait_vm0();
    if (lane == 0)
        __hip_atomic_fetch_add(myflag, 1u, __ATOMIC_RELAXED, __HIP_MEMORY_SCOPE_AGENT);

    // ---- phase C: per-lane state (wave-local reads of vsh) ----
    float rmast[4];   // fp32 master r: batch = 16mt+4quad+rg, feature = f0+n16
    #pragma unroll
    for (int rg = 0; rg < 4; ++rg) rmast[rg] = vsh[(16 * mt + 4 * quad + rg) * 16 + n16];
    const float l1c = lam1[f0 + n16];
    float l2c[BDN];
    #pragma unroll
    for (int k = 0; k < BDN; ++k) l2c[k] = lam2[k * RESN + f0 + n16];
    __syncthreads();   // all vsh/hf reads done before weight overwrite

    // ---- phase D: weight slice -> fragment-major LDS; stage Wr frags ----
    for (int e = tid; e < 2 * NMAT * 8 * 64; e += NTHR) {
        int l  = e & 63;
        int kk = (e >> 6) & 7;
        int m  = e >> 9;
        int pl = (m >= NMAT) ? 1 : 0;
        int nt = m - pl * NMAT;
        const uint4* src = (const uint4*)(wbf + (size_t)pl * PLANE +
            (size_t)(nt * RESN + f0 + (l & 15)) * RESN + kk * 32 + (l >> 4) * 8);
        *(uint4*)&wlds[pl][nt][kk][l][0] = *src;
    }
    for (int p = tid; p < 512; p += NTHR) {   // Wr hi/lo 1-row B-frags
        int s = p >> 3, j = p & 7;
        int pl = s >> 5, kk = (s >> 2) & 7, q = s & 3;
        float v = Wr[kk * 32 + q * 8 + j];
        __hip_bfloat16 hi = __float2bfloat16(v);
        wrlds[pl][kk][q][j] = pl ? __builtin_bit_cast(short, __float2bfloat16(v - __bfloat162float(hi)))
                                 : __builtin_bit_cast(short, hi);
    }
    if (tid < 8) zfrag[tid] = 0;
    __syncthreads();

    const short* ph = (n16 == 0) ? &wrlds[0][0][quad][0] : &zfrag[0];
    const short* pw = (n16 == 0) ? &wrlds[1][0][quad][0] : &zfrag[0];
    const int    stp = (n16 == 0) ? 4 * 8 : 0;

    // ---- main loop: barrier-free ----
    for (int t = 0; t < L_T - 1; ++t) {
        // dw loads (independent of exchange) issued first
        float dwv[4][8];
        #pragma unroll
        for (int rg = 0; rg < 4; ++rg) {
            const size_t bglob = (size_t)(b0g + 16 * mt + 4 * quad + rg) * (L_T * BDN);
            const float4 d0 = *(const float4*)(inc + bglob + (size_t)(t + 1) * BDN);
            const float4 d1 = *(const float4*)(inc + bglob + (size_t)(t + 1) * BDN + 4);
            dwv[rg][0] = d0.x; dwv[rg][1] = d0.y; dwv[rg][2] = d0.z; dwv[rg][3] = d0.w;
            dwv[rg][4] = d1.x; dwv[rg][5] = d1.y; dwv[rg][6] = d1.z; dwv[rg][7] = d1.w;
            if (t == 0) {
                const float4 e0 = *(const float4*)(inc + bglob);
                const float4 e1 = *(const float4*)(inc + bglob + 4);
                dwv[rg][0] += e0.x; dwv[rg][1] += e0.y; dwv[rg][2] += e0.z; dwv[rg][3] += e0.w;
                dwv[rg][4] += e1.x; dwv[rg][5] += e1.y; dwv[rg][6] += e1.z; dwv[rg][7] += e1.w;
            }
        }
        spin_all(fladdr, (unsigned)(t + 1));
        const int cur = t & 1, nxt = cur ^ 1;
        const int lead = t & 15;   // rotating leader for the out column

        // A-frags: 16 wide MALL loads, single waitcnt, then unpack
        uint4 ua[16];
        {
            const unsigned* rbc = rbg + (size_t)(cur * BG + 16 * mt + n16) * RESN + quad * 8;
            #pragma unroll
            for (int kk = 0; kk < 8; ++kk) {
                ua[2 * kk]     = mall_load4(rbc + kk * 32);
                ua[2 * kk + 1] = mall_load4(rbc + kk * 32 + 4);
            }
        }
        wait_vm0();
        bf16x8 afh[8], afl[8];
        #pragma unroll
        for (int kk = 0; kk < 8; ++kk) {
            const uint4 a = ua[2 * kk], b = ua[2 * kk + 1];
            unsigned hw[4], lw[4];
            hw[0] = __builtin_amdgcn_perm(a.y, a.x, 0x05040100u);
            hw[1] = __builtin_amdgcn_perm(a.w, a.z, 0x05040100u);
            hw[2] = __builtin_amdgcn_perm(b.y, b.x, 0x05040100u);
            hw[3] = __builtin_amdgcn_perm(b.w, b.z, 0x05040100u);
            lw[0] = __builtin_amdgcn_perm(a.y, a.x, 0x07060302u);
            lw[1] = __builtin_amdgcn_perm(a.w, a.z, 0x07060302u);
            lw[2] = __builtin_amdgcn_perm(b.y, b.x, 0x07060302u);
            lw[3] = __builtin_amdgcn_perm(b.w, b.z, 0x07060302u);
            afh[kk] = __builtin_bit_cast(bf16x8, *(__attribute__((ext_vector_type(4))) unsigned*)hw);
            afl[kk] = __builtin_bit_cast(bf16x8, *(__attribute__((ext_vector_type(4))) unsigned*)lw);
        }

        // 9 matvecs, 3-term double-bf16: ah*bh + al*bh + ah*bl
        f32x4 acc[NMAT] = {};
        #pragma unroll
        for (int kk = 0; kk < 8; ++kk) {
            bf16x8 bh[NMAT], bl[NMAT];
            #pragma unroll
            for (int nt = 0; nt < NMAT; ++nt) {
                bh[nt] = *(const bf16x8*)&wlds[0][nt][kk][lane][0];
                bl[nt] = *(const bf16x8*)&wlds[1][nt][kk][lane][0];
            }
            #pragma unroll
            for (int nt = 0; nt < NMAT; ++nt)
                acc[nt] = __builtin_amdgcn_mfma_f32_16x16x32_bf16(afh[kk], bh[nt], acc[nt], 0, 0, 0);
            #pragma unroll
            for (int nt = 0; nt < NMAT; ++nt)
                acc[nt] = __builtin_amdgcn_mfma_f32_16x16x32_bf16(afl[kk], bh[nt], acc[nt], 0, 0, 0);
            #pragma unroll
            for (int nt = 0; nt < NMAT; ++nt)
                acc[nt] = __builtin_amdgcn_mfma_f32_16x16x32_bf16(afh[kk], bl[nt], acc[nt], 0, 0, 0);
        }

        // combine, publish slice; per-wave ack + flag post (no barrier)
        #pragma unroll
        for (int rg = 0; rg < 4; ++rg) {
            const int bl_ = 16 * mt + 4 * quad + rg;
            float drift = fast_tanh(rho1 * acc[0][rg] + rho2 * l1c);
            float s = 0.0f;
            #pragma unroll
            for (int k = 0; k < BDN; ++k)
                s += fast_tanh(rho3 * acc[1 + k][rg] + rho4 * l2c[k]) * dwv[rg][k];
            float rn = rmast[rg] + drift + rho5 * s;
            rmast[rg] = rn;
            mall_store1(&rbg[(nxt * BG + bl_) * RESN + f0 + n16], pack_hilo(rn));
        }
        wait_vm0();
        if (lane == 0)
            __hip_atomic_fetch_add(myflag, 1u, __ATOMIC_RELAXED, __HIP_MEMORY_SCOPE_AGENT);

        // out column t: rotating leader only, AFTER flag post (off critical path)
        if (fb == lead) {
            f32x4 accw = {};
            #pragma unroll
            for (int kk = 0; kk < 8; ++kk) {
                bf16x8 wh8 = *(const bf16x8*)(ph + kk * stp);
                bf16x8 wl8 = *(const bf16x8*)(pw + kk * stp);
                accw = __builtin_amdgcn_mfma_f32_16x16x32_bf16(afh[kk], wh8, accw, 0, 0, 0);
                accw = __builtin_amdgcn_mfma_f32_16x16x32_bf16(afl[kk], wh8, accw, 0, 0, 0);
                accw = __builtin_amdgcn_mfma_f32_16x16x32_bf16(afh[kk], wl8, accw, 0, 0, 0);
            }
            if (n16 == 0) {
                #pragma unroll
                for (int rg = 0; rg < 4; ++rg)
                    out[(size_t)(b0g + 16 * mt + 4 * quad + rg) * L_T + t] = accw[rg] + brv;
            }
        }
    }

    // ---- final column t = 127: leader fb == 127&15 == 15; r_127 in buf 1 ----
    if (fb == 15) {
        spin_all(fladdr, (unsigned)L_T);
        uint4 ua[16];
        const unsigned* rbc = rbg + (size_t)(1 * BG + 16 * mt + n16) * RESN + quad * 8;
        #pragma unroll
        for (int kk = 0; kk < 8; ++kk) {
            ua[2 * kk]     = mall_load4(rbc + kk * 32);
            ua[2 * kk + 1] = mall_load4(rbc + kk * 32 + 4);
        }
        wait_vm0();
        f32x4 accw = {};
        #pragma unroll
        for (int kk = 0; kk < 8; ++kk) {
            const uint4 a = ua[2 * kk], b = ua[2 * kk + 1];
            unsigned hw[4], lw[4];
            hw[0] = __builtin_amdgcn_perm(a.y, a.x, 0x05040100u);
            hw[1] = __builtin_amdgcn_perm(a.w, a.z, 0x05040100u);
            hw[2] = __builtin_amdgcn_perm(b.y, b.x, 0x05040100u);
            hw[3] = __builtin_amdgcn_perm(b.w, b.z, 0x05040100u);
            lw[0] = __builtin_amdgcn_perm(a.y, a.x, 0x07060302u);
            lw[1] = __builtin_amdgcn_perm(a.w, a.z, 0x07060302u);
            lw[2] = __builtin_amdgcn_perm(b.y, b.x, 0x07060302u);
            lw[3] = __builtin_amdgcn_perm(b.w, b.z, 0x07060302u);
            bf16x8 ah = __builtin_bit_cast(bf16x8, *(__attribute__((ext_vector_type(4))) unsigned*)hw);
            bf16x8 al = __builtin_bit_cast(bf16x8, *(__attribute__((ext_vector_type(4))) unsigned*)lw);
            bf16x8 wh8 = *(const bf16x8*)(ph + kk * stp);
            bf16x8 wl8 = *(const bf16x8*)(pw + kk * stp);
            accw = __builtin_amdgcn_mfma_f32_16x16x32_bf16(ah, wh8, accw, 0, 0, 0);
            accw = __builtin_amdgcn_mfma_f32_16x16x32_bf16(al, wh8, accw, 0, 0, 0);
            accw = __builtin_amdgcn_mfma_f32_16x16x32_bf16(ah, wl8, accw, 0, 0, 0);
        }
        if (n16 == 0) {
            #pragma unroll
            for (int rg = 0; rg < 4; ++rg)
                out[(size_t)(b0g + 16 * mt + 4 * quad + rg) * L_T + (L_T - 1)] = accw[rg] + brv;
        }
    }
}

extern "C" void kernel_launch(void* const* d_in, const int* in_sizes, int n_in,
                              void* d_out, int out_size, void* d_ws, size_t ws_size,
                              hipStream_t stream) {
    const float* Vn   = (const float*)d_in[0];
    const float* inc  = (const float*)d_in[1];
    const float* W1   = (const float*)d_in[2];
    const float* b1   = (const float*)d_in[3];
    const float* W2   = (const float*)d_in[4];
    const float* b2   = (const float*)d_in[5];
    const float* r1   = (const float*)d_in[6];
    const float* r2   = (const float*)d_in[7];
    const float* r3   = (const float*)d_in[8];
    const float* r4   = (const float*)d_in[9];
    const float* r5   = (const float*)d_in[10];
    const float* B1   = (const float*)d_in[11];
    const float* B2   = (const float*)d_in[12];
    const float* lam1 = (const float*)d_in[13];
    const float* lam2 = (const float*)d_in[14];
    const float* Wr   = (const float*)d_in[15];
    const float* br   = (const float*)d_in[16];

    __hip_bfloat16* wh    = (__hip_bfloat16*)d_ws;
    unsigned int*   rbu   = (unsigned int*)((char*)d_ws + WS_RB_OFF);
    unsigned int*   flags = (unsigned int*)((char*)d_ws + WS_FLAG_OFF);
    float* out = (float*)d_out;

    hipMemsetAsync(flags, 0, NGRP * FLAGS_PER_GRP * sizeof(unsigned int), stream);
    conv_w<<<dim3(NROWS * RESN / 256), dim3(256), 0, stream>>>(B1, B2, wh, wh + PLANE);
    sde_ws<<<dim3(256), dim3(NTHR), 0, stream>>>(
        Vn, inc, W1, b1, W2, b2, r1, r2, r3, r4, r5, lam1, lam2, Wr, br,
        wh, rbu, flags, out);
}